// Round 20
// baseline (390.668 us; speedup 1.0000x reference)
//
#include <hip/hip_runtime.h>

// SingleScaleSA: B=4, N=16384, S=2048, K=32, mlp 64 -> 64 -> 128, radius 0.2.
// FP32 I/O. Round 20: K-chunked tiles (32-wide) to shrink LDS and lift
// occupancy (layer3 66KB->34KB: 2->4 blocks/CU; layers1/2 -> ~26KB: 6/CU).
// poolMax stored transposed [ch][grp] for a coalesced finalize read.
constexpr int kNB    = 4;
constexpr int kNPts  = 16384;
constexpr int kNS    = 2048;
constexpr int kNK    = 32;
constexpr int kC3    = 128;
constexpr int kNRows = kNB * kNS * kNK;   // 262144
constexpr int kNGrp  = kNB * kNS;         // 8192
constexpr double kR2 = 0.2 * 0.2;

// ---------------------------------------------------------------- prep
__global__ __launch_bounds__(256) void ssaPrepKernel(
    const float* xyz, const float* newXyz,
    float* outHead, float4* soa, float* stats)
{
    int t = static_cast<int>(blockIdx.x) * 256 + static_cast<int>(threadIdx.x);
    if (t < kNB * kNPts) {
        soa[t] = make_float4(xyz[t * 3 + 0], xyz[t * 3 + 1], xyz[t * 3 + 2], 0.0f);
    }
    if (t < kNB * kNS * 3) {
        outHead[t] = newXyz[t];
    }
    if (t < 512) {
        stats[t] = 0.0f;
    }
}

// ---------------------------------------------------------------- ball query
__global__ __launch_bounds__(256) void ssaBallKernel(
    const float* newXyz, const float4* soa,
    int* ballIdx, float4* ballDxyz)
{
    int tid  = static_cast<int>(threadIdx.x);
    int w    = (static_cast<int>(blockIdx.x) * 256 + tid) >> 6;
    int lane = tid & 63;
    int b    = w >> 11;
    float qx = newXyz[w * 3 + 0];
    float qy = newXyz[w * 3 + 1];
    float qz = newXyz[w * 3 + 2];
    double qxd = static_cast<double>(qx);
    double qyd = static_cast<double>(qy);
    double qzd = static_cast<double>(qz);
    double qq  = qxd * qxd + qyd * qyd + qzd * qzd;
    const float4* sp = soa + b * kNPts;
    int*    oi = ballIdx  + static_cast<size_t>(w) * kNK;
    float4* od = ballDxyz + static_cast<size_t>(w) * kNK;

    int cnt = 0;
    int firstN = -1;
    float fdx = 0.0f, fdy = 0.0f, fdz = 0.0f;
    for (int base = 0; base < kNPts && cnt < kNK; base += 64) {
        float4 p = sp[base + lane];
        double pxd = static_cast<double>(p.x);
        double pyd = static_cast<double>(p.y);
        double pzd = static_cast<double>(p.z);
        double d2  = qq + (pxd * pxd + pyd * pyd + pzd * pzd)
                   - 2.0 * (qxd * pxd + qyd * pyd + qzd * pzd);
        bool hit   = (d2 <= kR2);
        unsigned long long m = __ballot(hit);
        int pos = cnt + __popcll(m & ((1ull << lane) - 1ull));
        if (hit && pos < kNK) {
            float dx = p.x - qx;
            float dy = p.y - qy;
            float dz = p.z - qz;
            oi[pos] = base + lane;
            od[pos] = make_float4(dx, dy, dz, 0.0f);
            if (pos == 0) { firstN = base + lane; fdx = dx; fdy = dy; fdz = dz; }
        }
        cnt += __popcll(m);
    }
    if (cnt < kNK) {
        unsigned long long hv = __ballot(firstN >= 0);
        int fi;
        float dx, dy, dz;
        if (hv != 0ull) {
            int src = __builtin_ctzll(hv);
            fi = __shfl(firstN, src);
            dx = __shfl(fdx, src);
            dy = __shfl(fdy, src);
            dz = __shfl(fdz, src);
        } else {
            float4 p = sp[kNPts - 1];
            fi = kNPts - 1;
            dx = p.x - qx;
            dy = p.y - qy;
            dz = p.z - qz;
        }
        for (int p2 = cnt + lane; p2 < kNK; p2 += 64) {
            oi[p2] = fi;
            od[p2] = make_float4(dx, dy, dz, 0.0f);
        }
    }
}

// ---------------------------------------------------------------- layer 1
// 128 rows x 64 cols per block. dxyz folded into acc init; 64 point-dims
// K-chunked 2x32. Fused per-channel stats -> stats[0..63] sum, [64..127] sq.
__global__ __launch_bounds__(256) void ssaLayer1Kernel(
    const float4* points, const float* w1, const float* bias1,
    const int* ballIdx, const float4* ballDxyz, float4* z1, float* stats)
{
    __shared__ float xT[32 * 128];    // 16 KB, [k][r] chunk
    __shared__ float sW[32 * 64];     //  8 KB, [k][c] chunk (point dims)
    __shared__ float sWx[3 * 64];     // xyz weight rows
    __shared__ float sB[64];
    __shared__ float sStat[128];
    int tid = static_cast<int>(threadIdx.x);
    int R0  = static_cast<int>(blockIdx.x) * 128;
    int ty  = tid >> 4;
    int tx  = tid & 15;

    if (tid < 64) {
        sB[tid] = bias1[tid];
        sWx[0 * 64 + tid] = w1[tid * 67 + 0];
        sWx[1 * 64 + tid] = w1[tid * 67 + 1];
        sWx[2 * 64 + tid] = w1[tid * 67 + 2];
    }
    if (tid < 128) sStat[tid] = 0.0f;
    __syncthreads();

    float acc[8][4];
    #pragma unroll
    for (int i = 0; i < 8; i++) {
        int R = R0 + ty * 8 + i;
        float4 d = ballDxyz[R];
        #pragma unroll
        for (int j = 0; j < 4; j++) {
            int c = tx * 4 + j;
            acc[i][j] = sB[c] + d.x * sWx[c] + d.y * sWx[64 + c] + d.z * sWx[128 + c];
        }
    }

    int r = tid & 127;
    int h = tid >> 7;
    int gi = ballIdx[R0 + r];
    int b  = (R0 + r) >> 16;
    const float4* prow = points + (static_cast<size_t>(b) * kNPts + static_cast<size_t>(gi)) * 16;

    for (int ch = 0; ch < 2; ch++) {
        // stage W chunk: w1[c*67 + 3 + ch*32 + k]
        for (int i = tid; i < 32 * 64; i += 256) {
            int k = i >> 6;
            int c = i & 63;
            sW[i] = w1[c * 67 + 3 + ch * 32 + k];
        }
        // stage X chunk transposed: point dims [ch*32, ch*32+32)
        for (int j = h * 4; j < h * 4 + 4; j++) {
            float4 v = prow[ch * 8 + j];
            int k = j * 4;
            xT[(k + 0) * 128 + r] = v.x;
            xT[(k + 1) * 128 + r] = v.y;
            xT[(k + 2) * 128 + r] = v.z;
            xT[(k + 3) * 128 + r] = v.w;
        }
        __syncthreads();

        for (int k = 0; k < 32; k++) {
            const float* xk = &xT[k * 128 + ty * 8];
            const float* wk = &sW[k * 64 + tx * 4];
            float w0 = wk[0], w1v = wk[1], w2v = wk[2], w3v = wk[3];
            #pragma unroll
            for (int i = 0; i < 8; i++) {
                float xv = xk[i];
                acc[i][0] += xv * w0;
                acc[i][1] += xv * w1v;
                acc[i][2] += xv * w2v;
                acc[i][3] += xv * w3v;
            }
        }
        __syncthreads();
    }

    float s[4] = {0.f, 0.f, 0.f, 0.f};
    float q[4] = {0.f, 0.f, 0.f, 0.f};
    #pragma unroll
    for (int i = 0; i < 8; i++) {
        int row = R0 + ty * 8 + i;
        z1[static_cast<size_t>(row) * 16 + tx] =
            make_float4(acc[i][0], acc[i][1], acc[i][2], acc[i][3]);
        #pragma unroll
        for (int j = 0; j < 4; j++) {
            s[j] += acc[i][j];
            q[j] += acc[i][j] * acc[i][j];
        }
    }
    int lane = tid & 63;
    #pragma unroll
    for (int j = 0; j < 4; j++) {
        s[j] += __shfl_xor(s[j], 16); q[j] += __shfl_xor(q[j], 16);
        s[j] += __shfl_xor(s[j], 32); q[j] += __shfl_xor(q[j], 32);
    }
    if (lane < 16) {
        #pragma unroll
        for (int j = 0; j < 4; j++) {
            atomicAdd(&sStat[tx * 4 + j],      s[j]);
            atomicAdd(&sStat[64 + tx * 4 + j], q[j]);
        }
    }
    __syncthreads();
    if (tid < 128) {
        atomicAdd(&stats[tid], sStat[tid]);
    }
}

// ---------------------------------------------------------------- layer 2
// 128 rows x 64 cols; BN1+ReLU while staging; K-chunked 2x32; fused stats.
__global__ __launch_bounds__(256) void ssaLayer2Kernel(
    const float4* z1, const float* w2, const float* bias2,
    const float* gamma1, const float* beta1, const float* statsIn,
    float4* z2, float* statsOut)
{
    __shared__ float xT[32 * 128];    // 16 KB
    __shared__ float sW[32 * 64];     //  8 KB
    __shared__ float sB[64];
    __shared__ float sG[64];
    __shared__ float sH[64];
    __shared__ float sStat[128];
    int tid = static_cast<int>(threadIdx.x);
    int R0  = static_cast<int>(blockIdx.x) * 128;
    int ty  = tid >> 4;
    int tx  = tid & 15;

    if (tid < 64) {
        sB[tid] = bias2[tid];
        double mean = static_cast<double>(statsIn[tid]) / static_cast<double>(kNRows);
        double var  = static_cast<double>(statsIn[64 + tid]) / static_cast<double>(kNRows) - mean * mean;
        double rstd = 1.0 / sqrt(var + 1e-5);
        float g = static_cast<float>(rstd) * gamma1[tid];
        sG[tid] = g;
        sH[tid] = beta1[tid] - static_cast<float>(mean) * g;
    }
    if (tid < 128) sStat[tid] = 0.0f;
    __syncthreads();

    float acc[8][4];
    #pragma unroll
    for (int i = 0; i < 8; i++)
        #pragma unroll
        for (int j = 0; j < 4; j++) acc[i][j] = sB[tx * 4 + j];

    int r = tid & 127;
    int h = tid >> 7;
    const float4* zr = z1 + static_cast<size_t>(R0 + r) * 16;

    for (int ch = 0; ch < 2; ch++) {
        for (int i = tid; i < 32 * 64; i += 256) {
            int k = i >> 6;
            int c = i & 63;
            sW[i] = w2[c * 64 + ch * 32 + k];
        }
        for (int j = h * 4; j < h * 4 + 4; j++) {
            float4 v = zr[ch * 8 + j];
            int kg = ch * 32 + j * 4;
            int k  = j * 4;
            xT[(k + 0) * 128 + r] = fmaxf(v.x * sG[kg + 0] + sH[kg + 0], 0.0f);
            xT[(k + 1) * 128 + r] = fmaxf(v.y * sG[kg + 1] + sH[kg + 1], 0.0f);
            xT[(k + 2) * 128 + r] = fmaxf(v.z * sG[kg + 2] + sH[kg + 2], 0.0f);
            xT[(k + 3) * 128 + r] = fmaxf(v.w * sG[kg + 3] + sH[kg + 3], 0.0f);
        }
        __syncthreads();

        for (int k = 0; k < 32; k++) {
            const float* xk = &xT[k * 128 + ty * 8];
            const float* wk = &sW[k * 64 + tx * 4];
            float w0 = wk[0], w1v = wk[1], w2v = wk[2], w3v = wk[3];
            #pragma unroll
            for (int i = 0; i < 8; i++) {
                float xv = xk[i];
                acc[i][0] += xv * w0;
                acc[i][1] += xv * w1v;
                acc[i][2] += xv * w2v;
                acc[i][3] += xv * w3v;
            }
        }
        __syncthreads();
    }

    float s[4] = {0.f, 0.f, 0.f, 0.f};
    float q[4] = {0.f, 0.f, 0.f, 0.f};
    #pragma unroll
    for (int i = 0; i < 8; i++) {
        int row = R0 + ty * 8 + i;
        z2[static_cast<size_t>(row) * 16 + tx] =
            make_float4(acc[i][0], acc[i][1], acc[i][2], acc[i][3]);
        #pragma unroll
        for (int j = 0; j < 4; j++) {
            s[j] += acc[i][j];
            q[j] += acc[i][j] * acc[i][j];
        }
    }
    int lane = tid & 63;
    #pragma unroll
    for (int j = 0; j < 4; j++) {
        s[j] += __shfl_xor(s[j], 16); q[j] += __shfl_xor(q[j], 16);
        s[j] += __shfl_xor(s[j], 32); q[j] += __shfl_xor(q[j], 32);
    }
    if (lane < 16) {
        #pragma unroll
        for (int j = 0; j < 4; j++) {
            atomicAdd(&sStat[tx * 4 + j],      s[j]);
            atomicAdd(&sStat[64 + tx * 4 + j], q[j]);
        }
    }
    __syncthreads();
    if (tid < 128) {
        atomicAdd(&statsOut[tid], sStat[tid]);
    }
}

// ---------------------------------------------------------------- layer 3
// 128 rows x 128 cols; K-chunked 2x32; pre-BN wave max-pool (wave g owns
// group g's 32 rows); poolMax written transposed [ch][grp]; fused BN3 stats.
__global__ __launch_bounds__(256) void ssaLayer3Kernel(
    const float4* z2, const float* w3, const float* bias3,
    const float* gamma2, const float* beta2, const float* statsIn,
    float* poolMaxT, float* statsOut)
{
    __shared__ float xT[32 * 128];    // 16 KB
    __shared__ float sW[32 * 128];    // 16 KB
    __shared__ float sB[128];
    __shared__ float sG[64];
    __shared__ float sH[64];
    __shared__ float sStat[256];
    int tid = static_cast<int>(threadIdx.x);
    int R0  = static_cast<int>(blockIdx.x) * 128;
    int ty  = tid >> 4;
    int tx  = tid & 15;

    if (tid < 64) {
        double mean = static_cast<double>(statsIn[tid]) / static_cast<double>(kNRows);
        double var  = static_cast<double>(statsIn[64 + tid]) / static_cast<double>(kNRows) - mean * mean;
        double rstd = 1.0 / sqrt(var + 1e-5);
        float g = static_cast<float>(rstd) * gamma2[tid];
        sG[tid] = g;
        sH[tid] = beta2[tid] - static_cast<float>(mean) * g;
    }
    if (tid < 128) sB[tid] = bias3[tid];
    if (tid < 256) sStat[tid] = 0.0f;
    __syncthreads();

    float acc[8][8];
    #pragma unroll
    for (int i = 0; i < 8; i++)
        #pragma unroll
        for (int j = 0; j < 8; j++) acc[i][j] = sB[tx * 8 + j];

    int r = tid & 127;
    int h = tid >> 7;
    const float4* zr = z2 + static_cast<size_t>(R0 + r) * 16;

    for (int ch = 0; ch < 2; ch++) {
        for (int i = tid; i < 32 * 128; i += 256) {
            int k = i >> 7;
            int c = i & 127;
            sW[i] = w3[c * 64 + ch * 32 + k];
        }
        for (int j = h * 4; j < h * 4 + 4; j++) {
            float4 v = zr[ch * 8 + j];
            int kg = ch * 32 + j * 4;
            int k  = j * 4;
            xT[(k + 0) * 128 + r] = fmaxf(v.x * sG[kg + 0] + sH[kg + 0], 0.0f);
            xT[(k + 1) * 128 + r] = fmaxf(v.y * sG[kg + 1] + sH[kg + 1], 0.0f);
            xT[(k + 2) * 128 + r] = fmaxf(v.z * sG[kg + 2] + sH[kg + 2], 0.0f);
            xT[(k + 3) * 128 + r] = fmaxf(v.w * sG[kg + 3] + sH[kg + 3], 0.0f);
        }
        __syncthreads();

        for (int k = 0; k < 32; k++) {
            const float* xk = &xT[k * 128 + ty * 8];
            const float* wk = &sW[k * 128 + tx * 8];
            float wv[8];
            #pragma unroll
            for (int j = 0; j < 8; j++) wv[j] = wk[j];
            #pragma unroll
            for (int i = 0; i < 8; i++) {
                float xv = xk[i];
                #pragma unroll
                for (int j = 0; j < 8; j++) {
                    acc[i][j] += xv * wv[j];
                }
            }
        }
        __syncthreads();
    }

    // pooling (max over the wave's 32 rows) + stats
    int lane = tid & 63;
    int grp  = static_cast<int>(blockIdx.x) * 4 + (ty >> 2);
    float mx[8];
    float s[8];
    float q[8];
    #pragma unroll
    for (int j = 0; j < 8; j++) {
        mx[j] = acc[0][j];
        s[j]  = 0.0f;
        q[j]  = 0.0f;
    }
    #pragma unroll
    for (int i = 0; i < 8; i++)
        #pragma unroll
        for (int j = 0; j < 8; j++) {
            float v = acc[i][j];
            mx[j] = fmaxf(mx[j], v);
            s[j] += v;
            q[j] += v * v;
        }
    #pragma unroll
    for (int j = 0; j < 8; j++) {
        mx[j] = fmaxf(mx[j], __shfl_xor(mx[j], 16));
        mx[j] = fmaxf(mx[j], __shfl_xor(mx[j], 32));
        s[j] += __shfl_xor(s[j], 16); q[j] += __shfl_xor(q[j], 16);
        s[j] += __shfl_xor(s[j], 32); q[j] += __shfl_xor(q[j], 32);
    }
    if (lane < 16) {
        #pragma unroll
        for (int j = 0; j < 8; j++) {
            poolMaxT[static_cast<size_t>(tx * 8 + j) * kNGrp + grp] = mx[j];
            atomicAdd(&sStat[tx * 8 + j],       s[j]);
            atomicAdd(&sStat[128 + tx * 8 + j], q[j]);
        }
    }
    __syncthreads();
    if (tid < 256) {
        atomicAdd(&statsOut[tid], sStat[tid]);
    }
}

// ---------------------------------------------------------------- finalize
// outTail[b][ch][s] = relu(BN3(poolMaxT[ch][b*kNS+s])) — coalesced read.
__global__ __launch_bounds__(256) void ssaFinalKernel(
    const float* poolMaxT, const float* sum3, const float* sq3,
    const float* gamma3, const float* beta3, float* outTail)
{
    __shared__ float sG[128];
    __shared__ float sH[128];
    int tid = static_cast<int>(threadIdx.x);
    if (tid < 128) {
        double mean = static_cast<double>(sum3[tid]) / static_cast<double>(kNRows);
        double var  = static_cast<double>(sq3[tid]) / static_cast<double>(kNRows) - mean * mean;
        double rstd = 1.0 / sqrt(var + 1e-5);
        float g = static_cast<float>(rstd) * gamma3[tid];
        sG[tid] = g;
        sH[tid] = beta3[tid] - static_cast<float>(mean) * g;
    }
    __syncthreads();
    int e  = static_cast<int>(blockIdx.x) * 256 + tid;
    int b  = e >> 18;
    int ch = (e >> 11) & 127;
    int s  = e & 2047;
    size_t gi = static_cast<size_t>(ch) * kNGrp + b * kNS + s;
    outTail[e] = fmaxf(poolMaxT[gi] * sG[ch] + sH[ch], 0.0f);
}

// ---------------------------------------------------------------- launch
static inline void* ssaWsAt(void* base, size_t byteOff)
{
    return static_cast<void*>(static_cast<char*>(base) + byteOff);
}

extern "C" __attribute__((visibility("default"), used))
void kernel_launch(void* const* d_in, const int* in_sizes, int n_in,
                   void* d_out, int out_size, void* d_ws, size_t ws_size,
                   hipStream_t stream)
{
    static_cast<void>(in_sizes);
    static_cast<void>(n_in);
    static_cast<void>(out_size);
    static_cast<void>(ws_size);

    const float*  xyz    = static_cast<const float*>(d_in[0]);
    const float4* points = static_cast<const float4*>(d_in[1]);
    const float*  newXyz = static_cast<const float*>(d_in[2]);
    const float*  w1Ptr  = static_cast<const float*>(d_in[3]);
    const float*  b1Ptr  = static_cast<const float*>(d_in[4]);
    const float*  g1Ptr  = static_cast<const float*>(d_in[5]);
    const float*  e1Ptr  = static_cast<const float*>(d_in[6]);
    const float*  w2Ptr  = static_cast<const float*>(d_in[7]);
    const float*  b2Ptr  = static_cast<const float*>(d_in[8]);
    const float*  g2Ptr  = static_cast<const float*>(d_in[9]);
    const float*  e2Ptr  = static_cast<const float*>(d_in[10]);
    const float*  w3Ptr  = static_cast<const float*>(d_in[11]);
    const float*  b3Ptr  = static_cast<const float*>(d_in[12]);
    const float*  g3Ptr  = static_cast<const float*>(d_in[13]);
    const float*  e3Ptr  = static_cast<const float*>(d_in[14]);

    float4* soa   = static_cast<float4*>(ssaWsAt(d_ws, 0));           //   1,048,576 B
    int*    bIdx  = static_cast<int*>(ssaWsAt(d_ws, 1048576));        //   1,048,576 B
    float4* bDxy  = static_cast<float4*>(ssaWsAt(d_ws, 2097152));     //   4,194,304 B
    float4* z1    = static_cast<float4*>(ssaWsAt(d_ws, 6291456));     //  67,108,864 B
    float4* z2    = static_cast<float4*>(ssaWsAt(d_ws, 73400320));    //  67,108,864 B
    float*  pMax  = static_cast<float*>(ssaWsAt(d_ws, 140509184));    //   4,194,304 B
    float*  stats = static_cast<float*>(ssaWsAt(d_ws, 144703488));    //   2,048 B
    float*  outF  = static_cast<float*>(d_out);

    ssaPrepKernel<<<256, 256, 0, stream>>>(xyz, newXyz, outF, soa, stats);
    ssaBallKernel<<<kNGrp / 4, 256, 0, stream>>>(newXyz, soa, bIdx, bDxy);
    ssaLayer1Kernel<<<kNRows / 128, 256, 0, stream>>>(points, w1Ptr, b1Ptr, bIdx, bDxy,
                                                      z1, stats);
    ssaLayer2Kernel<<<kNRows / 128, 256, 0, stream>>>(z1, w2Ptr, b2Ptr, g1Ptr, e1Ptr,
                                                      stats, z2, stats + 128);
    ssaLayer3Kernel<<<kNRows / 128, 256, 0, stream>>>(z2, w3Ptr, b3Ptr, g2Ptr, e2Ptr,
                                                      stats + 128, pMax, stats + 256);
    ssaFinalKernel<<<kNB * kC3 * kNS / 256, 256, 0, stream>>>(pMax, stats + 256, stats + 384,
                                                              g3Ptr, e3Ptr,
                                                              outF + kNB * kNS * 3);
}